// Round 1
// baseline (17614.981 us; speedup 1.0000x reference)
//
#include <hip/hip_runtime.h>
#include <hip/hip_bf16.h>
#include <math.h>

// GPT-2-ish forward: V=50257, C=1024, H=16, L=8, B=2, T=1024, D=64
#define V_ 50257
#define C_ 1024
#define H_ 16
#define L_ 8
#define B_ 2
#define T_ 1024
#define D_ 64
#define BT_ (B_*T_)

__device__ __forceinline__ float wave_sum(float v){
  #pragma unroll
  for(int o=32;o>0;o>>=1) v += __shfl_down(v,o,64);
  return v;
}
__device__ __forceinline__ float wave_max(float v){
  #pragma unroll
  for(int o=32;o>0;o>>=1) v = fmaxf(v, __shfl_down(v,o,64));
  return v;
}

// x[b,t,c] = tok_emb[idx[b,t],c] + pos_emb[t,c]
__global__ __launch_bounds__(256) void embed_kernel(const int* __restrict__ idx,
    const float* __restrict__ tok, const float* __restrict__ pos, float* __restrict__ x){
  int i = blockIdx.x*256 + threadIdx.x;        // over BT*C (exact multiple)
  int c = i & (C_-1); int bt = i >> 10; int t = bt & (T_-1);
  x[i] = tok[(size_t)idx[bt]*C_ + c] + pos[t*C_ + c];
}

// LayerNorm over C=1024; one 256-thread block per row; safe in-place (in==out).
__global__ __launch_bounds__(256) void ln_kernel(const float* in, const float* __restrict__ w,
    const float* __restrict__ b, float* out){
  int row = blockIdx.x;
  const float* xr = in + (size_t)row*C_;
  float vals[4]; float sum=0.f, sq=0.f;
  #pragma unroll
  for(int l=0;l<4;l++){ float v = xr[threadIdx.x + l*256]; vals[l]=v; sum+=v; sq+=v*v; }
  __shared__ float r1[4], r2[4];
  float s1 = wave_sum(sum), s2 = wave_sum(sq);
  int wid = threadIdx.x>>6, lane = threadIdx.x&63;
  if(lane==0){ r1[wid]=s1; r2[wid]=s2; }
  __syncthreads();
  float tot  = r1[0]+r1[1]+r1[2]+r1[3];
  float tot2 = r2[0]+r2[1]+r2[2]+r2[3];
  float mu  = tot * (1.f/C_);
  float var = tot2 * (1.f/C_) - mu*mu;
  float inv = rsqrtf(var + 1e-5f);
  float* orow = out + (size_t)row*C_;
  #pragma unroll
  for(int l=0;l<4;l++){ int c = threadIdx.x + l*256; orow[c] = (vals[l]-mu)*inv*w[c] + b[c]; }
}

// C[m,n] = act( A[m,:] . W[n,:] + bias[n] ) + resid[m,n]
// A:[M,K] row-major, W:[N,K] row-major (torch Linear). 64x64 tile, BK=16,
// 256 thr, 4x4 micro-tile. LDS k-major (pad 68) -> b128 fragment reads.
// resid/Cm may alias (same-element read-then-write per thread) -> no restrict.
__global__ __launch_bounds__(256) void gemm_nt(const float* __restrict__ A, const float* __restrict__ W,
    const float* __restrict__ bias, const float* resid, float* Cm,
    int M, int N, int K, int act){
  __shared__ float As[16][68];
  __shared__ float Bs[16][68];
  int m0 = blockIdx.y*64, n0 = blockIdx.x*64;
  int tid = threadIdx.x;
  int tx = tid & 15, ty = tid >> 4;
  float acc[4][4] = {};
  for(int k0=0;k0<K;k0+=16){
    #pragma unroll
    for(int l=0;l<4;l++){
      int li = tid + l*256;
      int r = li >> 4, c = li & 15;
      int gm = m0 + r, gn = n0 + r, gk = k0 + c;   // K always mult of 16
      As[c][r] = (gm<M) ? A[(size_t)gm*K + gk] : 0.f;
      Bs[c][r] = (gn<N) ? W[(size_t)gn*K + gk] : 0.f;
    }
    __syncthreads();
    #pragma unroll
    for(int k=0;k<16;k++){
      float4 av = *(const float4*)&As[k][ty*4];
      float4 bv = *(const float4*)&Bs[k][tx*4];
      float a[4] = {av.x, av.y, av.z, av.w};
      float b4[4] = {bv.x, bv.y, bv.z, bv.w};
      #pragma unroll
      for(int i=0;i<4;i++)
        #pragma unroll
        for(int j=0;j<4;j++)
          acc[i][j] = fmaf(a[i], b4[j], acc[i][j]);
    }
    __syncthreads();
  }
  #pragma unroll
  for(int i=0;i<4;i++){
    int m = m0 + ty*4 + i; if(m>=M) continue;
    #pragma unroll
    for(int j=0;j<4;j++){
      int n = n0 + tx*4 + j; if(n>=N) continue;
      float v = acc[i][j];
      if(bias) v += bias[n];
      if(act)  v = 0.5f*v*(1.f + erff(v*0.70710678118654752f));
      if(resid) v += resid[(size_t)m*N + n];
      Cm[(size_t)m*N + n] = v;
    }
  }
}

// att[bh,i,j] = 0.125 * q[b,i,h,:].k[b,j,h,:]  (only lower-tri 32x32 tiles)
__global__ __launch_bounds__(256) void qk_kernel(const float* __restrict__ q,
    const float* __restrict__ k, float* __restrict__ att){
  int jt = blockIdx.x, it = blockIdx.y;
  if (jt > it) return;                       // upper tiles never read
  int bh = blockIdx.z; int b = bh >> 4, h = bh & 15;
  __shared__ float qs[32][68], ks[32][68];
  int tid = threadIdx.x;
  #pragma unroll
  for(int l=0;l<2;l++){
    int li = tid + l*256;
    int r = li >> 4, c4 = li & 15;
    *(float4*)&qs[r][c4*4] = *(const float4*)(q + (size_t)(b*T_ + it*32 + r)*C_ + h*64 + c4*4);
    *(float4*)&ks[r][c4*4] = *(const float4*)(k + (size_t)(b*T_ + jt*32 + r)*C_ + h*64 + c4*4);
  }
  __syncthreads();
  int tx = tid & 31, ty = tid >> 5;          // j = tx, i = ty*4+ii
  float acc[4] = {};
  #pragma unroll
  for(int d0=0; d0<64; d0+=4){
    float4 kv = *(const float4*)&ks[tx][d0];
    #pragma unroll
    for(int ii=0;ii<4;ii++){
      float4 qv = *(const float4*)&qs[ty*4+ii][d0];
      acc[ii] += qv.x*kv.x + qv.y*kv.y + qv.z*kv.z + qv.w*kv.w;
    }
  }
  #pragma unroll
  for(int ii=0;ii<4;ii++){
    int i = it*32 + ty*4 + ii, j = jt*32 + tx;
    att[((size_t)bh*T_ + i)*T_ + j] = (j<=i) ? acc[ii]*0.125f : -1e30f;
  }
}

// causal row softmax: row (bh,i) has i+1 valid entries
__global__ __launch_bounds__(256) void softmax_kernel(float* __restrict__ att){
  int row = blockIdx.x;                      // [0, B*H*T)
  int i = row & (T_-1);
  float* p = att + (size_t)row*T_;
  int n = i + 1;
  float mx = -1e30f;
  for(int j=threadIdx.x; j<n; j+=256) mx = fmaxf(mx, p[j]);
  __shared__ float r1[4], r2[4];
  float wm = wave_max(mx);
  int wid = threadIdx.x>>6, lane = threadIdx.x&63;
  if(lane==0) r1[wid]=wm;
  __syncthreads();
  mx = fmaxf(fmaxf(r1[0],r1[1]), fmaxf(r1[2],r1[3]));
  float sum = 0.f;
  for(int j=threadIdx.x;j<n;j+=256){ float e = expf(p[j]-mx); p[j]=e; sum += e; }
  float ws = wave_sum(sum);
  if(lane==0) r2[wid]=ws;
  __syncthreads();
  float inv = 1.f/(r2[0]+r2[1]+r2[2]+r2[3]);
  for(int j=threadIdx.x;j<n;j+=256) p[j] *= inv;
}

// y[b,i,h,:] = sum_{j<=i} att[bh,i,j] * v[b,j,h,:]
__global__ __launch_bounds__(256) void av_kernel(const float* __restrict__ att,
    const float* __restrict__ v, float* __restrict__ y){
  int it = blockIdx.x; int bh = blockIdx.y; int b = bh>>4, h = bh&15;
  __shared__ float ps[32][33];
  __shared__ float vs[32][68];
  int tid = threadIdx.x;
  int tx = tid & 63, ty = tid >> 6;          // d = tx; rows i_local = r*4+ty
  float acc[8] = {};
  for(int jt=0; jt<=it; jt++){
    #pragma unroll
    for(int l=0;l<4;l++){
      int li = tid + l*256; int r = li>>5, c = li&31;
      int ig = it*32 + r, jg = jt*32 + c;
      float pv = att[((size_t)bh*T_ + ig)*T_ + jg];
      ps[r][c] = (jg<=ig) ? pv : 0.f;        // mask garbage above diagonal
    }
    #pragma unroll
    for(int l=0;l<2;l++){
      int li = tid + l*256; int r = li>>4, c4 = li&15;
      *(float4*)&vs[r][c4*4] = *(const float4*)(v + (size_t)(b*T_ + jt*32 + r)*C_ + h*64 + c4*4);
    }
    __syncthreads();
    #pragma unroll
    for(int j=0;j<32;j++){
      float vv = vs[j][tx];
      #pragma unroll
      for(int r=0;r<8;r++) acc[r] += ps[r*4+ty][j] * vv;
    }
    __syncthreads();
  }
  #pragma unroll
  for(int r=0;r<8;r++){
    int i = it*32 + r*4 + ty;
    y[(size_t)(b*T_ + i)*C_ + h*64 + tx] = acc[r];
  }
}

extern "C" void kernel_launch(void* const* d_in, const int* in_sizes, int n_in,
                              void* d_out, int out_size, void* d_ws, size_t ws_size,
                              hipStream_t stream) {
  const int*   idx  = (const int*)  d_in[0];
  const float* tok  = (const float*)d_in[1];
  const float* pos  = (const float*)d_in[2];
  const float* Wq   = (const float*)d_in[3];
  const float* bq   = (const float*)d_in[4];
  const float* Wk   = (const float*)d_in[5];
  const float* bk   = (const float*)d_in[6];
  const float* Wv   = (const float*)d_in[7];
  const float* bv   = (const float*)d_in[8];
  const float* Wp   = (const float*)d_in[9];
  const float* bp   = (const float*)d_in[10];
  const float* ln1w = (const float*)d_in[11];
  const float* ln1b = (const float*)d_in[12];
  const float* ln2w = (const float*)d_in[13];
  const float* ln2b = (const float*)d_in[14];
  const float* W1   = (const float*)d_in[15];
  const float* b1   = (const float*)d_in[16];
  const float* W2   = (const float*)d_in[17];
  const float* b2   = (const float*)d_in[18];
  const float* lnfw = (const float*)d_in[19];
  const float* lnfb = (const float*)d_in[20];
  const float* headw= (const float*)d_in[21];

  float* out = (float*)d_out;
  // d_out (102,926,336 floats) doubles as scratch until the head GEMM:
  //   att 33,554,432 | mlp 8,388,608 | q,k,v,y,h 5x2,097,152  = 52,428,800 total
  float* att  = out;
  float* mbuf = out + 33554432;
  float* qb   = out + 41943040;
  float* kb   = qb + 2097152;
  float* vb   = kb + 2097152;
  float* yb   = vb + 2097152;
  float* hb   = yb + 2097152;
  float* x    = (float*)d_ws;   // residual stream (8 MB) — must survive head GEMM

  embed_kernel<<<BT_*C_/256, 256, 0, stream>>>(idx, tok, pos, x);

  dim3 gCC(C_/64, BT_/64);           // 16 x 32 blocks
  for(int l=0;l<L_;l++){
    ln_kernel<<<BT_,256,0,stream>>>(x, ln1w + l*C_, ln1b + l*C_, hb);
    gemm_nt<<<gCC,256,0,stream>>>(hb, Wq + (size_t)l*C_*C_, bq + l*C_, nullptr, qb, BT_, C_, C_, 0);
    gemm_nt<<<gCC,256,0,stream>>>(hb, Wk + (size_t)l*C_*C_, bk + l*C_, nullptr, kb, BT_, C_, C_, 0);
    gemm_nt<<<gCC,256,0,stream>>>(hb, Wv + (size_t)l*C_*C_, bv + l*C_, nullptr, vb, BT_, C_, C_, 0);
    qk_kernel<<<dim3(T_/32, T_/32, B_*H_),256,0,stream>>>(qb, kb, att);
    softmax_kernel<<<B_*H_*T_,256,0,stream>>>(att);
    av_kernel<<<dim3(T_/32, B_*H_),256,0,stream>>>(att, vb, yb);
    gemm_nt<<<gCC,256,0,stream>>>(yb, Wp + (size_t)l*C_*C_, bp + l*C_, x, x, BT_, C_, C_, 0);
    ln_kernel<<<BT_,256,0,stream>>>(x, ln2w + l*C_, ln2b + l*C_, hb);
    gemm_nt<<<dim3(4*C_/64, BT_/64),256,0,stream>>>(hb, W1 + (size_t)l*4*C_*C_, b1 + (size_t)l*4*C_,
                                                    nullptr, mbuf, BT_, 4*C_, C_, 1);
    gemm_nt<<<gCC,256,0,stream>>>(mbuf, W2 + (size_t)l*C_*4*C_, b2 + l*C_, x, x, BT_, C_, 4*C_, 0);
  }
  ln_kernel<<<BT_,256,0,stream>>>(x, lnfw, lnfb, x);   // in-place: x dies here
  gemm_nt<<<dim3((V_+63)/64, BT_/64),256,0,stream>>>(x, headw, nullptr, nullptr, out,
                                                     BT_, V_, C_, 0);
}

// Round 2
// 5119.950 us; speedup vs baseline: 3.4405x; 3.4405x over previous
//
#include <hip/hip_runtime.h>
#include <math.h>

// GPT-2-ish forward: V=50257, C=1024, H=16, L=8, B=2, T=1024, D=64
#define V_ 50257
#define C_ 1024
#define H_ 16
#define L_ 8
#define B_ 2
#define T_ 1024
#define BT_ 2048
#define CC_ (C_*C_)
#define QLD_ 3072   // packed q|k|v row stride

typedef unsigned short ushort_t;
using bf16x8 = __attribute__((ext_vector_type(8))) short;
using f32x4  = __attribute__((ext_vector_type(4))) float;

__device__ __forceinline__ ushort_t f2bf(float f){
  union { float f; unsigned u; } a; a.f = f;
  unsigned r = a.u + 0x7fffu + ((a.u >> 16) & 1u);   // RNE
  return (ushort_t)(r >> 16);
}

__device__ __forceinline__ float wave_sum(float v){
  #pragma unroll
  for(int o=32;o>0;o>>=1) v += __shfl_down(v,o,64);
  return v;
}
__device__ __forceinline__ float wave_max(float v){
  #pragma unroll
  for(int o=32;o>0;o>>=1) v = fmaxf(v, __shfl_down(v,o,64));
  return v;
}

// ---------------- conversions ----------------
// d (ushort) gets src block blk at d4[blk*dstStride4 + r]; vector-4 elems.
__global__ __launch_bounds__(256) void cvt_blk(const float* __restrict__ s, ushort_t* __restrict__ d,
    long inner4, int nblk, long dstStride4){
  long total = inner4 * nblk;
  for(long i = (long)blockIdx.x*256 + threadIdx.x; i < total; i += (long)gridDim.x*256){
    long blk = i / inner4, r = i - blk*inner4;
    float4 v = ((const float4*)s)[i];
    ushort4 o; o.x=f2bf(v.x); o.y=f2bf(v.y); o.z=f2bf(v.z); o.w=f2bf(v.w);
    ((ushort4*)d)[blk*dstStride4 + r] = o;
  }
}

__global__ __launch_bounds__(256) void pack_qkv_bias(const float* __restrict__ bq,
    const float* __restrict__ bk, const float* __restrict__ bv, float* __restrict__ dst){
  int i = blockIdx.x*256 + threadIdx.x;          // L*3072
  int l = i / QLD_, c = i - l*QLD_;
  float v;
  if(c < C_)            v = bq[l*C_ + c];
  else if(c < 2*C_)     v = bk[l*C_ + c - C_];
  else                  v = bv[l*C_ + c - 2*C_];
  dst[i] = v;
}

// x[b,t,c] = tok_emb[idx[b,t],c] + pos_emb[t,c]
__global__ __launch_bounds__(256) void embed_kernel(const int* __restrict__ idx,
    const float* __restrict__ tok, const float* __restrict__ pos, float* __restrict__ x){
  int i = blockIdx.x*256 + threadIdx.x;
  int c = i & (C_-1); int bt = i >> 10; int t = bt & (T_-1);
  x[i] = tok[(size_t)idx[bt]*C_ + c] + pos[t*C_ + c];
}

// LayerNorm over C=1024; writes f32 (outF) or bf16 (outB). in==outF safe.
__global__ __launch_bounds__(256) void ln_kernel(const float* in, const float* __restrict__ w,
    const float* __restrict__ b, float* outF, ushort_t* outB){
  int row = blockIdx.x;
  const float* xr = in + (size_t)row*C_;
  float vals[4]; float sum=0.f, sq=0.f;
  #pragma unroll
  for(int l=0;l<4;l++){ float v = xr[threadIdx.x + l*256]; vals[l]=v; sum+=v; sq+=v*v; }
  __shared__ float r1[4], r2[4];
  float s1 = wave_sum(sum), s2 = wave_sum(sq);
  int wid = threadIdx.x>>6, lane = threadIdx.x&63;
  if(lane==0){ r1[wid]=s1; r2[wid]=s2; }
  __syncthreads();
  float tot  = r1[0]+r1[1]+r1[2]+r1[3];
  float tot2 = r2[0]+r2[1]+r2[2]+r2[3];
  float mu  = tot * (1.f/C_);
  float var = tot2 * (1.f/C_) - mu*mu;
  float inv = rsqrtf(var + 1e-5f);
  #pragma unroll
  for(int l=0;l<4;l++){
    int c = threadIdx.x + l*256;
    float v = (vals[l]-mu)*inv*w[c] + b[c];
    if(outB) outB[(size_t)row*C_ + c] = f2bf(v);
    else     outF[(size_t)row*C_ + c] = v;
  }
}

// ---------------- bf16 MFMA GEMM ----------------
// C[m,n] = epi( A[m,:].W[n,:] + bias[n] ) (+resid) ; A:[M,K] bf16, W:[N,K] bf16.
// BM=128, BN in {64,128}, BK=32, 256 thr = 4 waves (2x2), wave tile 64 x BN/2.
// LDS in fragment order: subtile s (16 rows x 32 k) = 1KB; lane l holds 16B at
// s*1024 + l*16 == row (l&15), k ((l>>4)*8..+8). global_load_lds dest is linear,
// per-lane global src provides the swizzle (guide §5 m173 pattern).
template<int BN>
__global__ __launch_bounds__(256) void gemm_mfma(
    const ushort_t* __restrict__ A, const ushort_t* __restrict__ W,
    const float* __restrict__ bias, const float* resid,
    float* outF, ushort_t* outB,
    int M, int N, int K, int act)
{
  constexpr int BM = 128;
  constexpr int NSA = BM/16;          // 8 A-subtiles
  constexpr int NSB = BN/16;          // 8 or 4 B-subtiles
  constexpr int NBF = BN/32;          // B frags per wave (4 or 2)
  __shared__ __align__(16) short sA[2][NSA*512];
  __shared__ __align__(16) short sB[2][NSB*512];
  const int tid  = threadIdx.x;
  const int lane = tid & 63, wid = tid >> 6;
  const int wr = wid >> 1, wc = wid & 1;
  const int m0 = blockIdx.y * BM, n0 = blockIdx.x * BN;
  const int r16 = lane & 15, kq = lane >> 4;

  auto stage = [&](int buf, int k0){
    #pragma unroll
    for(int s2=0; s2<2; ++s2){                  // A: 2 subtiles per wave
      int s = wid*2 + s2;
      const ushort_t* g = A + (size_t)(m0 + s*16 + r16)*K + k0 + kq*8;
      __builtin_amdgcn_global_load_lds((const __attribute__((address_space(1))) void*)g,
          (__attribute__((address_space(3))) void*)&sA[buf][s*512], 16, 0, 0);
    }
    #pragma unroll
    for(int s2=0; s2<NSB/4; ++s2){              // B: NSB/4 subtiles per wave
      int s = wid*(NSB/4) + s2;
      int gn = n0 + s*16 + r16; if(gn >= N) gn = N-1;   // head tail clamp
      const ushort_t* g = W + (size_t)gn*K + k0 + kq*8;
      __builtin_amdgcn_global_load_lds((const __attribute__((address_space(1))) void*)g,
          (__attribute__((address_space(3))) void*)&sB[buf][s*512], 16, 0, 0);
    }
  };

  f32x4 acc[4][NBF];
  #pragma unroll
  for(int i=0;i<4;i++)
    #pragma unroll
    for(int j=0;j<NBF;j++) acc[i][j] = (f32x4){0.f,0.f,0.f,0.f};

  const int NT = K >> 5;
  stage(0, 0);
  int cur = 0;
  for(int t=0; t<NT; ++t){
    __syncthreads();                  // drains vmcnt: tile t staged + prev reads done
    if(t+1 < NT) stage(cur^1, (t+1)*32);
    bf16x8 af[4], bfr[NBF];
    #pragma unroll
    for(int m=0;m<4;m++) af[m] = *(const bf16x8*)&sA[cur][(wr*4+m)*512 + lane*8];
    #pragma unroll
    for(int n=0;n<NBF;n++) bfr[n] = *(const bf16x8*)&sB[cur][(wc*NBF+n)*512 + lane*8];
    #pragma unroll
    for(int m=0;m<4;m++)
      #pragma unroll
      for(int n=0;n<NBF;n++)
        acc[m][n] = __builtin_amdgcn_mfma_f32_16x16x32_bf16(af[m], bfr[n], acc[m][n], 0, 0, 0);
    cur ^= 1;
  }

  // C/D layout (m89-verified): col = lane&15, row = (lane>>4)*4 + reg
  const int colb = n0 + wc*(BN/2);
  #pragma unroll
  for(int m=0;m<4;m++){
    int rowb = m0 + wr*64 + m*16 + kq*4;
    #pragma unroll
    for(int n=0;n<NBF;n++){
      int col = colb + n*16 + r16;
      if(col >= N) continue;
      float bv = bias ? bias[col] : 0.f;
      #pragma unroll
      for(int i=0;i<4;i++){
        int row = rowb + i;
        float v = acc[m][n][i] + bv;
        if(act) v = 0.5f*v*(1.f + erff(v*0.70710678118654752f));
        if(resid) v += resid[(size_t)row*N + col];
        if(outB) outB[(size_t)row*N + col] = f2bf(v);
        else     outF[(size_t)row*N + col] = v;
      }
    }
  }
}

// ---------------- attention (f32, packed qkv ld=3072) ----------------
__global__ __launch_bounds__(256) void qk_kernel(const float* __restrict__ qkv,
    float* __restrict__ att){
  int jt = blockIdx.x, it = blockIdx.y;
  if (jt > it) return;
  int bh = blockIdx.z; int b = bh >> 4, h = bh & 15;
  __shared__ float qs[32][68], ks[32][68];
  int tid = threadIdx.x;
  const float* q = qkv;
  const float* k = qkv + C_;
  #pragma unroll
  for(int l=0;l<2;l++){
    int li = tid + l*256;
    int r = li >> 4, c4 = li & 15;
    *(float4*)&qs[r][c4*4] = *(const float4*)(q + (size_t)(b*T_ + it*32 + r)*QLD_ + h*64 + c4*4);
    *(float4*)&ks[r][c4*4] = *(const float4*)(k + (size_t)(b*T_ + jt*32 + r)*QLD_ + h*64 + c4*4);
  }
  __syncthreads();
  int tx = tid & 31, ty = tid >> 5;
  float acc[4] = {};
  #pragma unroll
  for(int d0=0; d0<64; d0+=4){
    float4 kv = *(const float4*)&ks[tx][d0];
    #pragma unroll
    for(int ii=0;ii<4;ii++){
      float4 qv = *(const float4*)&qs[ty*4+ii][d0];
      acc[ii] += qv.x*kv.x + qv.y*kv.y + qv.z*kv.z + qv.w*kv.w;
    }
  }
  #pragma unroll
  for(int ii=0;ii<4;ii++){
    int i = it*32 + ty*4 + ii, j = jt*32 + tx;
    att[((size_t)bh*T_ + i)*T_ + j] = (j<=i) ? acc[ii]*0.125f : -1e30f;
  }
}

__global__ __launch_bounds__(256) void softmax_kernel(float* __restrict__ att){
  int row = blockIdx.x;
  int i = row & (T_-1);
  float* p = att + (size_t)row*T_;
  int n = i + 1;
  float mx = -1e30f;
  for(int j=threadIdx.x; j<n; j+=256) mx = fmaxf(mx, p[j]);
  __shared__ float r1[4], r2[4];
  float wm = wave_max(mx);
  int wid = threadIdx.x>>6, lane = threadIdx.x&63;
  if(lane==0) r1[wid]=wm;
  __syncthreads();
  mx = fmaxf(fmaxf(r1[0],r1[1]), fmaxf(r1[2],r1[3]));
  float sum = 0.f;
  for(int j=threadIdx.x;j<n;j+=256){ float e = expf(p[j]-mx); p[j]=e; sum += e; }
  float ws = wave_sum(sum);
  if(lane==0) r2[wid]=ws;
  __syncthreads();
  float inv = 1.f/(r2[0]+r2[1]+r2[2]+r2[3]);
  for(int j=threadIdx.x;j<n;j+=256) p[j] *= inv;
}

__global__ __launch_bounds__(256) void av_kernel(const float* __restrict__ att,
    const float* __restrict__ qkv, ushort_t* __restrict__ y){
  int it = blockIdx.x; int bh = blockIdx.y; int b = bh>>4, h = bh&15;
  const float* v = qkv + 2*C_;
  __shared__ float ps[32][33];
  __shared__ float vs[32][68];
  int tid = threadIdx.x;
  int tx = tid & 63, ty = tid >> 6;
  float acc[8] = {};
  for(int jt=0; jt<=it; jt++){
    #pragma unroll
    for(int l=0;l<4;l++){
      int li = tid + l*256; int r = li>>5, c = li&31;
      int ig = it*32 + r, jg = jt*32 + c;
      float pv = att[((size_t)bh*T_ + ig)*T_ + jg];
      ps[r][c] = (jg<=ig) ? pv : 0.f;
    }
    #pragma unroll
    for(int l=0;l<2;l++){
      int li = tid + l*256; int r = li>>4, c4 = li&15;
      *(float4*)&vs[r][c4*4] = *(const float4*)(v + (size_t)(b*T_ + jt*32 + r)*QLD_ + h*64 + c4*4);
    }
    __syncthreads();
    #pragma unroll
    for(int j=0;j<32;j++){
      float vv = vs[j][tx];
      #pragma unroll
      for(int r=0;r<8;r++) acc[r] += ps[r*4+ty][j] * vv;
    }
    __syncthreads();
  }
  #pragma unroll
  for(int r=0;r<8;r++){
    int i = it*32 + r*4 + ty;
    y[(size_t)(b*T_ + i)*C_ + h*64 + tx] = f2bf(acc[r]);
  }
}

// ---------------- f32 GEMM fallback (head only, if ws too small) ----------------
__global__ __launch_bounds__(256) void gemm_nt(const float* __restrict__ A, const float* __restrict__ W,
    const float* __restrict__ bias, const float* resid, float* Cm,
    int M, int N, int K, int act){
  __shared__ float As[16][68];
  __shared__ float Bs[16][68];
  int m0 = blockIdx.y*64, n0 = blockIdx.x*64;
  int tid = threadIdx.x;
  int tx = tid & 15, ty = tid >> 4;
  float acc[4][4] = {};
  for(int k0=0;k0<K;k0+=16){
    #pragma unroll
    for(int l=0;l<4;l++){
      int li = tid + l*256;
      int r = li >> 4, c = li & 15;
      int gm = m0 + r, gn = n0 + r, gk = k0 + c;
      As[c][r] = (gm<M) ? A[(size_t)gm*K + gk] : 0.f;
      Bs[c][r] = (gn<N) ? W[(size_t)gn*K + gk] : 0.f;
    }
    __syncthreads();
    #pragma unroll
    for(int k=0;k<16;k++){
      float4 av = *(const float4*)&As[k][ty*4];
      float4 bv = *(const float4*)&Bs[k][tx*4];
      float a[4] = {av.x, av.y, av.z, av.w};
      float b4[4] = {bv.x, bv.y, bv.z, bv.w};
      #pragma unroll
      for(int i=0;i<4;i++)
        #pragma unroll
        for(int j=0;j<4;j++)
          acc[i][j] = fmaf(a[i], b4[j], acc[i][j]);
    }
    __syncthreads();
  }
  #pragma unroll
  for(int i=0;i<4;i++){
    int m = m0 + ty*4 + i; if(m>=M) continue;
    #pragma unroll
    for(int j=0;j<4;j++){
      int n = n0 + tx*4 + j; if(n>=N) continue;
      float v = acc[i][j];
      if(bias) v += bias[n];
      if(act)  v = 0.5f*v*(1.f + erff(v*0.70710678118654752f));
      if(resid) v += resid[(size_t)m*N + n];
      Cm[(size_t)m*N + n] = v;
    }
  }
}

extern "C" void kernel_launch(void* const* d_in, const int* in_sizes, int n_in,
                              void* d_out, int out_size, void* d_ws, size_t ws_size,
                              hipStream_t stream) {
  const int*   idx  = (const int*)  d_in[0];
  const float* tok  = (const float*)d_in[1];
  const float* pos  = (const float*)d_in[2];
  const float* Wq   = (const float*)d_in[3];
  const float* bq   = (const float*)d_in[4];
  const float* Wk   = (const float*)d_in[5];
  const float* bk   = (const float*)d_in[6];
  const float* Wv   = (const float*)d_in[7];
  const float* bv   = (const float*)d_in[8];
  const float* Wp   = (const float*)d_in[9];
  const float* bp   = (const float*)d_in[10];
  const float* ln1w = (const float*)d_in[11];
  const float* ln1b = (const float*)d_in[12];
  const float* ln2w = (const float*)d_in[13];
  const float* ln2b = (const float*)d_in[14];
  const float* W1   = (const float*)d_in[15];
  const float* b1   = (const float*)d_in[16];
  const float* W2   = (const float*)d_in[17];
  const float* b2   = (const float*)d_in[18];
  const float* lnfw = (const float*)d_in[19];
  const float* lnfb = (const float*)d_in[20];
  const float* headw= (const float*)d_in[21];

  float* out = (float*)d_out;
  // d_out (102,926,336 f32) as scratch arena until the head GEMM overwrites it:
  float*    att  = out;                               // 33,554,432 f
  float*    qkvf = out + 33554432;                    //  6,291,456 f  (f32 q|k|v, ld 3072)
  ushort_t* hb   = (ushort_t*)(out + 39845888);       //  2,097,152 bf16 (LN out)
  ushort_t* yb   = (ushort_t*)(out + 40894464);       //  2,097,152 bf16 (attn out)
  ushort_t* mb   = (ushort_t*)(out + 41943040);       //  8,388,608 bf16 (GELU out)
  ushort_t* wqkv = (ushort_t*)(out + 46137344);       // 25,165,824 bf16
  ushort_t* wpb  = (ushort_t*)(out + 58720256);       //  8,388,608 bf16
  ushort_t* w1b  = (ushort_t*)(out + 62914560);       // 33,554,432 bf16
  ushort_t* w2b  = (ushort_t*)(out + 79691776);       // 33,554,432 bf16
  float*    bqkv = out + 96468992;                    //     24,576 f
  float*    x    = (float*)d_ws;                      //  2,097,152 f residual
  ushort_t* xb   = (ushort_t*)((float*)d_ws + 2097152);
  ushort_t* whb  = (ushort_t*)((float*)d_ws + 3145728); // 51,463,168 bf16
  const bool big = ws_size >= (size_t)28877312 * 4;   // room for xb + whb?

  // weight conversions (f32 -> bf16), all independent
  cvt_blk<<<2048,256,0,stream>>>(Wq, wqkv,          CC_/4, L_, 3*CC_/4);
  cvt_blk<<<2048,256,0,stream>>>(Wk, wqkv + CC_,    CC_/4, L_, 3*CC_/4);
  cvt_blk<<<2048,256,0,stream>>>(Wv, wqkv + 2*CC_,  CC_/4, L_, 3*CC_/4);
  cvt_blk<<<2048,256,0,stream>>>(Wp, wpb,  (long)L_*CC_/4,   1, (long)L_*CC_/4);
  cvt_blk<<<2048,256,0,stream>>>(W1, w1b,  (long)L_*CC_,     1, (long)L_*CC_);   // 8*4CC/4
  cvt_blk<<<2048,256,0,stream>>>(W2, w2b,  (long)L_*CC_,     1, (long)L_*CC_);
  if(big) cvt_blk<<<2048,256,0,stream>>>(headw, whb, (long)V_*C_/4, 1, (long)V_*C_/4);
  pack_qkv_bias<<<L_*QLD_/256,256,0,stream>>>(bq, bk, bv, bqkv);

  embed_kernel<<<BT_*C_/256, 256, 0, stream>>>(idx, tok, pos, x);

  for(int l=0;l<L_;l++){
    ln_kernel<<<BT_,256,0,stream>>>(x, ln1w + l*C_, ln1b + l*C_, nullptr, hb);
    gemm_mfma<128><<<dim3(QLD_/128, BT_/128),256,0,stream>>>(hb, wqkv + (size_t)l*3*CC_,
        bqkv + l*QLD_, nullptr, qkvf, nullptr, BT_, QLD_, C_, 0);
    qk_kernel<<<dim3(T_/32, T_/32, B_*H_),256,0,stream>>>(qkvf, att);
    softmax_kernel<<<B_*H_*T_,256,0,stream>>>(att);
    av_kernel<<<dim3(T_/32, B_*H_),256,0,stream>>>(att, qkvf, yb);
    gemm_mfma<64><<<dim3(C_/64, BT_/128),256,0,stream>>>(yb, wpb + (size_t)l*CC_,
        bp + l*C_, x, x, nullptr, BT_, C_, C_, 0);
    ln_kernel<<<BT_,256,0,stream>>>(x, ln2w + l*C_, ln2b + l*C_, nullptr, hb);
    gemm_mfma<128><<<dim3(4*C_/128, BT_/128),256,0,stream>>>(hb, w1b + (size_t)l*4*CC_,
        b1 + (size_t)l*4*C_, nullptr, nullptr, mb, BT_, 4*C_, C_, 1);
    gemm_mfma<64><<<dim3(C_/64, BT_/128),256,0,stream>>>(mb, w2b + (size_t)l*4*CC_,
        b2 + l*C_, x, x, nullptr, BT_, C_, 4*C_, 0);
  }

  if(big){
    ln_kernel<<<BT_,256,0,stream>>>(x, lnfw, lnfb, nullptr, xb);
    gemm_mfma<128><<<dim3((V_+127)/128, BT_/128),256,0,stream>>>(xb, whb,
        nullptr, nullptr, out, nullptr, BT_, V_, C_, 0);
  } else {
    ln_kernel<<<BT_,256,0,stream>>>(x, lnfw, lnfb, x, nullptr);
    gemm_nt<<<dim3((V_+63)/64, BT_/64),256,0,stream>>>(x, headw, nullptr, nullptr, out,
                                                       BT_, V_, C_, 0);
  }
}

// Round 3
// 2921.091 us; speedup vs baseline: 6.0303x; 1.7528x over previous
//
#include <hip/hip_runtime.h>
#include <math.h>

// GPT-2-ish forward: V=50257, C=1024, H=16, L=8, B=2, T=1024, D=64
#define V_ 50257
#define C_ 1024
#define H_ 16
#define L_ 8
#define B_ 2
#define T_ 1024
#define BT_ 2048
#define CC_ (C_*C_)
#define QLD_ 3072   // packed q|k|v row stride (bf16)

typedef unsigned short ushort_t;
using bf16x8 = __attribute__((ext_vector_type(8))) short;
using f32x4  = __attribute__((ext_vector_type(4))) float;

__device__ __forceinline__ ushort_t f2bf(float f){
  union { float f; unsigned u; } a; a.f = f;
  unsigned r = a.u + 0x7fffu + ((a.u >> 16) & 1u);   // RNE
  return (ushort_t)(r >> 16);
}

__device__ __forceinline__ float wave_sum(float v){
  #pragma unroll
  for(int o=32;o>0;o>>=1) v += __shfl_down(v,o,64);
  return v;
}
__device__ __forceinline__ float wave_max(float v){
  #pragma unroll
  for(int o=32;o>0;o>>=1) v = fmaxf(v, __shfl_down(v,o,64));
  return v;
}

// ---------------- conversions ----------------
__global__ __launch_bounds__(256) void cvt_blk(const float* __restrict__ s, ushort_t* __restrict__ d,
    long inner4, int nblk, long dstStride4){
  long total = inner4 * nblk;
  for(long i = (long)blockIdx.x*256 + threadIdx.x; i < total; i += (long)gridDim.x*256){
    long blk = i / inner4, r = i - blk*inner4;
    float4 v = ((const float4*)s)[i];
    ushort4 o; o.x=f2bf(v.x); o.y=f2bf(v.y); o.z=f2bf(v.z); o.w=f2bf(v.w);
    ((ushort4*)d)[blk*dstStride4 + r] = o;
  }
}

__global__ __launch_bounds__(256) void pack_qkv_bias(const float* __restrict__ bq,
    const float* __restrict__ bk, const float* __restrict__ bv, float* __restrict__ dst){
  int i = blockIdx.x*256 + threadIdx.x;          // L*3072
  int l = i / QLD_, c = i - l*QLD_;
  float v;
  if(c < C_)            v = bq[l*C_ + c];
  else if(c < 2*C_)     v = bk[l*C_ + c - C_];
  else                  v = bv[l*C_ + c - 2*C_];
  dst[i] = v;
}

__global__ __launch_bounds__(256) void embed_kernel(const int* __restrict__ idx,
    const float* __restrict__ tok, const float* __restrict__ pos, float* __restrict__ x){
  int i = blockIdx.x*256 + threadIdx.x;
  int c = i & (C_-1); int bt = i >> 10; int t = bt & (T_-1);
  x[i] = tok[(size_t)idx[bt]*C_ + c] + pos[t*C_ + c];
}

// LayerNorm over C=1024; writes f32 (outF) or bf16 (outB). in==outF safe.
__global__ __launch_bounds__(256) void ln_kernel(const float* in, const float* __restrict__ w,
    const float* __restrict__ b, float* outF, ushort_t* outB){
  int row = blockIdx.x;
  const float* xr = in + (size_t)row*C_;
  float vals[4]; float sum=0.f, sq=0.f;
  #pragma unroll
  for(int l=0;l<4;l++){ float v = xr[threadIdx.x + l*256]; vals[l]=v; sum+=v; sq+=v*v; }
  __shared__ float r1[4], r2[4];
  float s1 = wave_sum(sum), s2 = wave_sum(sq);
  int wid = threadIdx.x>>6, lane = threadIdx.x&63;
  if(lane==0){ r1[wid]=s1; r2[wid]=s2; }
  __syncthreads();
  float tot  = r1[0]+r1[1]+r1[2]+r1[3];
  float tot2 = r2[0]+r2[1]+r2[2]+r2[3];
  float mu  = tot * (1.f/C_);
  float var = tot2 * (1.f/C_) - mu*mu;
  float inv = rsqrtf(var + 1e-5f);
  #pragma unroll
  for(int l=0;l<4;l++){
    int c = threadIdx.x + l*256;
    float v = (vals[l]-mu)*inv*w[c] + b[c];
    if(outB) outB[(size_t)row*C_ + c] = f2bf(v);
    else     outF[(size_t)row*C_ + c] = v;
  }
}

// ---------------- bf16 MFMA GEMM ----------------
// grid: (x = M/128, y = N/BN)  -- M-fastest for weight-panel L2/L3 reuse.
template<int BN>
__global__ __launch_bounds__(256) void gemm_mfma(
    const ushort_t* __restrict__ A, const ushort_t* __restrict__ W,
    const float* __restrict__ bias, const float* resid,
    float* outF, ushort_t* outB,
    int M, int N, int K, int act)
{
  constexpr int BM = 128;
  constexpr int NSA = BM/16;          // 8 A-subtiles
  constexpr int NSB = BN/16;          // 8 or 4 B-subtiles
  constexpr int NBF = BN/32;          // B frags per wave (4 or 2)
  __shared__ __align__(16) short sA[2][NSA*512];
  __shared__ __align__(16) short sB[2][NSB*512];
  const int tid  = threadIdx.x;
  const int lane = tid & 63, wid = tid >> 6;
  const int wr = wid >> 1, wc = wid & 1;
  const int m0 = blockIdx.x * BM, n0 = blockIdx.y * BN;
  const int r16 = lane & 15, kq = lane >> 4;

  auto stage = [&](int buf, int k0){
    #pragma unroll
    for(int s2=0; s2<2; ++s2){                  // A: 2 subtiles per wave
      int s = wid*2 + s2;
      const ushort_t* g = A + (size_t)(m0 + s*16 + r16)*K + k0 + kq*8;
      __builtin_amdgcn_global_load_lds((const __attribute__((address_space(1))) void*)g,
          (__attribute__((address_space(3))) void*)&sA[buf][s*512], 16, 0, 0);
    }
    #pragma unroll
    for(int s2=0; s2<NSB/4; ++s2){              // B: NSB/4 subtiles per wave
      int s = wid*(NSB/4) + s2;
      int gn = n0 + s*16 + r16; if(gn >= N) gn = N-1;   // head tail clamp
      const ushort_t* g = W + (size_t)gn*K + k0 + kq*8;
      __builtin_amdgcn_global_load_lds((const __attribute__((address_space(1))) void*)g,
          (__attribute__((address_space(3))) void*)&sB[buf][s*512], 16, 0, 0);
    }
  };

  f32x4 acc[4][NBF];
  #pragma unroll
  for(int i=0;i<4;i++)
    #pragma unroll
    for(int j=0;j<NBF;j++) acc[i][j] = (f32x4){0.f,0.f,0.f,0.f};

  const int NT = K >> 5;
  stage(0, 0);
  int cur = 0;
  for(int t=0; t<NT; ++t){
    __syncthreads();
    if(t+1 < NT) stage(cur^1, (t+1)*32);
    bf16x8 af[4], bfr[NBF];
    #pragma unroll
    for(int m=0;m<4;m++) af[m] = *(const bf16x8*)&sA[cur][(wr*4+m)*512 + lane*8];
    #pragma unroll
    for(int n=0;n<NBF;n++) bfr[n] = *(const bf16x8*)&sB[cur][(wc*NBF+n)*512 + lane*8];
    #pragma unroll
    for(int m=0;m<4;m++)
      #pragma unroll
      for(int n=0;n<NBF;n++)
        acc[m][n] = __builtin_amdgcn_mfma_f32_16x16x32_bf16(af[m], bfr[n], acc[m][n], 0, 0, 0);
    cur ^= 1;
  }

  // C/D layout: col = lane&15, row = (lane>>4)*4 + reg
  const int colb = n0 + wc*(BN/2);
  #pragma unroll
  for(int m=0;m<4;m++){
    int rowb = m0 + wr*64 + m*16 + kq*4;
    #pragma unroll
    for(int n=0;n<NBF;n++){
      int col = colb + n*16 + r16;
      if(col >= N) continue;
      float bv = bias ? bias[col] : 0.f;
      #pragma unroll
      for(int i=0;i<4;i++){
        int row = rowb + i;
        float v = acc[m][n][i] + bv;
        if(act) v = 0.5f*v*(1.f + erff(v*0.70710678118654752f));
        if(resid) v += resid[(size_t)row*N + col];
        if(outB) outB[(size_t)row*N + col] = f2bf(v);
        else     outF[(size_t)row*N + col] = v;
      }
    }
  }
}

// ---------------- fused flash attention (bf16 MFMA) ----------------
__global__ __launch_bounds__(256) void flash_kernel(const ushort_t* __restrict__ qkv,
    ushort_t* __restrict__ y){
  const int tid = threadIdx.x, lane = tid & 63, wid = tid >> 6;
  const int r16 = lane & 15, kq = lane >> 4;
  const int qt = blockIdx.x, bh = blockIdx.y, b = bh >> 4, h = bh & 15;
  const int q0 = qt*64, qw0 = q0 + wid*16;
  const int qa = qw0 + r16;

  __shared__ __align__(16) short Kt[4][512];
  __shared__ __align__(16) short VT[64][36];
  __shared__ __align__(16) short Pl[4][16][36];
  __shared__ __align__(16) short Ol[4][16][68];

  const size_t rowQ = (size_t)(b*T_ + qw0 + r16)*QLD_ + h*64 + kq*8;
  bf16x8 qf0 = *(const bf16x8*)(qkv + rowQ);
  bf16x8 qf1 = *(const bf16x8*)(qkv + rowQ + 32);

  f32x4 acc[4];
  #pragma unroll
  for(int t=0;t<4;t++) acc[t] = (f32x4){0.f,0.f,0.f,0.f};
  float m_r = -INFINITY, l_r = 0.f;

  const int njt = q0/32 + 2;
  for(int jt=0; jt<njt; ++jt){
    __syncthreads();
    {
      const ushort_t* g = qkv + (size_t)(b*T_ + jt*32 + (wid>>1)*16 + r16)*QLD_
                          + C_ + h*64 + (wid&1)*32 + kq*8;
      __builtin_amdgcn_global_load_lds((const __attribute__((address_space(1))) void*)g,
          (__attribute__((address_space(3))) void*)&Kt[wid][lane*8], 16, 0, 0);
    }
    {
      int k = tid >> 3, d0 = (tid & 7)*8;
      bf16x8 vv = *(const bf16x8*)(qkv + (size_t)(b*T_ + jt*32 + k)*QLD_ + 2*C_ + h*64 + d0);
      #pragma unroll
      for(int j=0;j<8;j++) VT[d0+j][k] = vv[j];
    }
    __syncthreads();

    if(jt*32 <= qw0 + 15){
      f32x4 st0 = (f32x4){0.f,0.f,0.f,0.f}, st1 = st0;
      st0 = __builtin_amdgcn_mfma_f32_16x16x32_bf16(*(const bf16x8*)&Kt[0][lane*8], qf0, st0, 0,0,0);
      st0 = __builtin_amdgcn_mfma_f32_16x16x32_bf16(*(const bf16x8*)&Kt[1][lane*8], qf1, st0, 0,0,0);
      st1 = __builtin_amdgcn_mfma_f32_16x16x32_bf16(*(const bf16x8*)&Kt[2][lane*8], qf0, st1, 0,0,0);
      st1 = __builtin_amdgcn_mfma_f32_16x16x32_bf16(*(const bf16x8*)&Kt[3][lane*8], qf1, st1, 0,0,0);

      float vals[8]; float mx = m_r;
      #pragma unroll
      for(int s=0;s<2;s++){
        #pragma unroll
        for(int i=0;i<4;i++){
          int ka = jt*32 + 16*s + 4*kq + i;
          float v = (s? st1[i] : st0[i]) * 0.125f;
          v = (ka <= qa) ? v : -INFINITY;
          vals[s*4+i] = v; mx = fmaxf(mx, v);
        }
      }
      mx = fmaxf(mx, __shfl_xor(mx, 16, 64));
      mx = fmaxf(mx, __shfl_xor(mx, 32, 64));
      float alpha = __expf(m_r - mx);
      float ps = 0.f;
      #pragma unroll
      for(int idx=0; idx<8; idx++){
        float p = __expf(vals[idx] - mx);
        ps += p;
        Pl[wid][r16][(idx>>2)*16 + 4*kq + (idx&3)] = (short)f2bf(p);
      }
      ps += __shfl_xor(ps, 16, 64);
      ps += __shfl_xor(ps, 32, 64);
      l_r = l_r*alpha + ps; m_r = mx;
      #pragma unroll
      for(int t=0;t<4;t++)
        #pragma unroll
        for(int j=0;j<4;j++) acc[t][j] *= alpha;

      union { bf16x8 v8; uint2 u2[2]; } pf, vf;
      pf.u2[0] = *(const uint2*)&Pl[wid][r16][kq*8];
      pf.u2[1] = *(const uint2*)&Pl[wid][r16][kq*8 + 4];
      #pragma unroll
      for(int db=0; db<4; db++){
        vf.u2[0] = *(const uint2*)&VT[16*db + r16][kq*8];
        vf.u2[1] = *(const uint2*)&VT[16*db + r16][kq*8 + 4];
        acc[db] = __builtin_amdgcn_mfma_f32_16x16x32_bf16(vf.v8, pf.v8, acc[db], 0,0,0);
      }
    }
  }

  float linv = 1.f / l_r;
  #pragma unroll
  for(int db=0; db<4; db++)
    #pragma unroll
    for(int i=0;i<4;i++)
      Ol[wid][r16][16*db + 4*kq + i] = (short)f2bf(acc[db][i]*linv);
  int q = lane >> 2, c0 = (lane & 3)*16;
  const short* src = &Ol[wid][q][c0];
  uint2 a0 = *(const uint2*)(src+0), a1 = *(const uint2*)(src+4);
  uint2 a2 = *(const uint2*)(src+8), a3 = *(const uint2*)(src+12);
  ushort_t* dst = y + (size_t)(b*T_ + qw0 + q)*C_ + h*64 + c0;
  uint4 w0 = {a0.x, a0.y, a1.x, a1.y}, w1 = {a2.x, a2.y, a3.x, a3.y};
  *(uint4*)(dst+0) = w0;
  *(uint4*)(dst+8) = w1;
}

// ---------------- f32 GEMM fallback (head only, if ws too small) ----------------
__global__ __launch_bounds__(256) void gemm_nt(const float* __restrict__ A, const float* __restrict__ W,
    const float* __restrict__ bias, const float* resid, float* Cm,
    int M, int N, int K, int act){
  __shared__ float As[16][68];
  __shared__ float Bs[16][68];
  int m0 = blockIdx.y*64, n0 = blockIdx.x*64;
  int tid = threadIdx.x;
  int tx = tid & 15, ty = tid >> 4;
  float acc[4][4] = {};
  for(int k0=0;k0<K;k0+=16){
    #pragma unroll
    for(int l=0;l<4;l++){
      int li = tid + l*256;
      int r = li >> 4, c = li & 15;
      int gm = m0 + r, gn = n0 + r, gk = k0 + c;
      As[c][r] = (gm<M) ? A[(size_t)gm*K + gk] : 0.f;
      Bs[c][r] = (gn<N) ? W[(size_t)gn*K + gk] : 0.f;
    }
    __syncthreads();
    #pragma unroll
    for(int k=0;k<16;k++){
      float4 av = *(const float4*)&As[k][ty*4];
      float4 bv = *(const float4*)&Bs[k][tx*4];
      float a[4] = {av.x, av.y, av.z, av.w};
      float b4[4] = {bv.x, bv.y, bv.z, bv.w};
      #pragma unroll
      for(int i=0;i<4;i++)
        #pragma unroll
        for(int j=0;j<4;j++)
          acc[i][j] = fmaf(a[i], b4[j], acc[i][j]);
    }
    __syncthreads();
  }
  #pragma unroll
  for(int i=0;i<4;i++){
    int m = m0 + ty*4 + i; if(m>=M) continue;
    #pragma unroll
    for(int j=0;j<4;j++){
      int n = n0 + tx*4 + j; if(n>=N) continue;
      float v = acc[i][j];
      if(bias) v += bias[n];
      if(act)  v = 0.5f*v*(1.f + erff(v*0.70710678118654752f));
      if(resid) v += resid[(size_t)m*N + n];
      Cm[(size_t)m*N + n] = v;
    }
  }
}

extern "C" void kernel_launch(void* const* d_in, const int* in_sizes, int n_in,
                              void* d_out, int out_size, void* d_ws, size_t ws_size,
                              hipStream_t stream) {
  const int*   idx  = (const int*)  d_in[0];
  const float* tok  = (const float*)d_in[1];
  const float* pos  = (const float*)d_in[2];
  const float* Wq   = (const float*)d_in[3];
  const float* bq   = (const float*)d_in[4];
  const float* Wk   = (const float*)d_in[5];
  const float* bk   = (const float*)d_in[6];
  const float* Wv   = (const float*)d_in[7];
  const float* bv   = (const float*)d_in[8];
  const float* Wp   = (const float*)d_in[9];
  const float* bp   = (const float*)d_in[10];
  const float* ln1w = (const float*)d_in[11];
  const float* ln1b = (const float*)d_in[12];
  const float* ln2w = (const float*)d_in[13];
  const float* ln2b = (const float*)d_in[14];
  const float* W1   = (const float*)d_in[15];
  const float* b1   = (const float*)d_in[16];
  const float* W2   = (const float*)d_in[17];
  const float* b2   = (const float*)d_in[18];
  const float* lnfw = (const float*)d_in[19];
  const float* lnfb = (const float*)d_in[20];
  const float* headw= (const float*)d_in[21];

  float* out = (float*)d_out;
  ushort_t* qkvb = (ushort_t*)(out);                  //  6,291,456 bf16
  ushort_t* hb   = (ushort_t*)(out + 3145728);        //  2,097,152 bf16
  ushort_t* yb   = (ushort_t*)(out + 4194304);        //  2,097,152 bf16
  ushort_t* mb   = (ushort_t*)(out + 5242880);        //  8,388,608 bf16
  ushort_t* wqkv = (ushort_t*)(out + 9437184);        // 25,165,824 bf16
  ushort_t* wpb  = (ushort_t*)(out + 22020096);       //  8,388,608 bf16
  ushort_t* w1b  = (ushort_t*)(out + 26214400);       // 33,554,432 bf16
  ushort_t* w2b  = (ushort_t*)(out + 42991616);       // 33,554,432 bf16
  float*    bqkv = out + 59768832;                    //     24,576 f
  float*    x    = (float*)d_ws;
  ushort_t* xb   = (ushort_t*)((float*)d_ws + 2097152);
  ushort_t* whb  = (ushort_t*)((float*)d_ws + 3145728);
  const bool big = ws_size >= (size_t)28877312 * 4;

  cvt_blk<<<2048,256,0,stream>>>(Wq, wqkv,          CC_/4, L_, 3*CC_/4);
  cvt_blk<<<2048,256,0,stream>>>(Wk, wqkv + CC_,    CC_/4, L_, 3*CC_/4);
  cvt_blk<<<2048,256,0,stream>>>(Wv, wqkv + 2*CC_,  CC_/4, L_, 3*CC_/4);
  cvt_blk<<<2048,256,0,stream>>>(Wp, wpb,  (long)L_*CC_/4,   1, (long)L_*CC_/4);
  cvt_blk<<<2048,256,0,stream>>>(W1, w1b,  (long)L_*CC_,     1, (long)L_*CC_);
  cvt_blk<<<2048,256,0,stream>>>(W2, w2b,  (long)L_*CC_,     1, (long)L_*CC_);
  if(big) cvt_blk<<<2048,256,0,stream>>>(headw, whb, (long)V_*C_/4, 1, (long)V_*C_/4);
  pack_qkv_bias<<<L_*QLD_/256,256,0,stream>>>(bq, bk, bv, bqkv);

  embed_kernel<<<BT_*C_/256, 256, 0, stream>>>(idx, tok, pos, x);

  for(int l=0;l<L_;l++){
    ln_kernel<<<BT_,256,0,stream>>>(x, ln1w + l*C_, ln1b + l*C_, nullptr, hb);
    gemm_mfma<128><<<dim3(BT_/128, QLD_/128),256,0,stream>>>(hb, wqkv + (size_t)l*3*CC_,
        bqkv + l*QLD_, nullptr, nullptr, qkvb, BT_, QLD_, C_, 0);
    flash_kernel<<<dim3(T_/64, B_*H_),256,0,stream>>>(qkvb, yb);
    gemm_mfma<64><<<dim3(BT_/128, C_/64),256,0,stream>>>(yb, wpb + (size_t)l*CC_,
        bp + l*C_, x, x, nullptr, BT_, C_, C_, 0);
    ln_kernel<<<BT_,256,0,stream>>>(x, ln2w + l*C_, ln2b + l*C_, nullptr, hb);
    gemm_mfma<128><<<dim3(BT_/128, 4*C_/128),256,0,stream>>>(hb, w1b + (size_t)l*4*CC_,
        b1 + (size_t)l*4*C_, nullptr, nullptr, mb, BT_, 4*C_, C_, 1);
    gemm_mfma<64><<<dim3(BT_/128, C_/64),256,0,stream>>>(mb, w2b + (size_t)l*4*CC_,
        b2 + l*C_, x, x, nullptr, BT_, C_, 4*C_, 0);
  }

  if(big){
    ln_kernel<<<BT_,256,0,stream>>>(x, lnfw, lnfb, nullptr, xb);
    gemm_mfma<128><<<dim3(BT_/128, (V_+127)/128),256,0,stream>>>(xb, whb,
        nullptr, nullptr, out, nullptr, BT_, V_, C_, 0);
  } else {
    ln_kernel<<<BT_,256,0,stream>>>(x, lnfw, lnfb, x, nullptr);
    gemm_nt<<<dim3((V_+63)/64, BT_/64),256,0,stream>>>(x, headw, nullptr, nullptr, out,
                                                       BT_, V_, C_, 0);
  }
}